// Round 13
// baseline (164.717 us; speedup 1.0000x reference)
//
#include <hip/hip_runtime.h>
#include <math.h>

// Problem constants
#define D      128
#define NQ     512          // B * LQ = 4 * 128
#define LCTX   65536
#define TOPN   8
#define NCAND  16           // coarse candidates refined in f64
// Distance-kernel tiling
#define QT     128          // queries per block (8 waves x 16)
#define CCHUNK 512          // contexts per block
#define CSTEP  128          // contexts staged per LDS step
#define NCH    (LCTX / CCHUNK)    // 128 chunks
#define PERCHUNK 16               // candidates stored per (query, chunk)
#define NCANDTOT (NCH * PERCHUNK) // 2048 coarse candidates per query
#define NQT    (NQ / QT)          // 4 query tiles
#define NROWS  (LCTX + NQ)        // packed table rows (contexts then queries)
#define PACKB  (NROWS / 8)        // 8256 pack blocks
#define QPREPB (NQ / 8)           // 64 qprep blocks
#define FINF   3.0e38f

typedef __attribute__((ext_vector_type(8))) __bf16 bf16x8;
typedef __attribute__((ext_vector_type(4))) float f32x4;

// pack two f32 -> two bf16 (round-to-nearest-ish; coarse path only)
static __device__ __forceinline__ unsigned pack2(float a, float b) {
  const unsigned ua = (__float_as_uint(a) + 0x8000u) >> 16;
  const unsigned ub = (__float_as_uint(b) + 0x8000u) & 0xffff0000u;
  return ua | ub;
}

// ---------------------------------------------------------------------------
// Kernel 1 (fused prep): blocks [0,PACKB) gather+pack all rows to bf16 cemb
// (chunk-XOR-pre-swizzled) + cn2; blocks [PACKB,PACKB+QPREPB) compute
// qp = q @ W + b.  Block 0 also zero-inits the select finisher counter
// (re-done every launch -> graph-replay safe).
__global__ __launch_bounds__(256) void prep_kernel(const int* __restrict__ ctok,
                                                   const int* __restrict__ qtok,
                                                   const float* __restrict__ emb,
                                                   const float* __restrict__ W,
                                                   const float* __restrict__ bvec,
                                                   unsigned short* __restrict__ cemb,
                                                   float* __restrict__ cn2,
                                                   float* __restrict__ qp,
                                                   unsigned* __restrict__ cnt) {
  __shared__ float sW[32 * D];  // 16 KB (qprep path)
  __shared__ float sq[8][D];    // 4 KB
  const int tid = threadIdx.x;

  if (blockIdx.x < PACKB) {
    if (blockIdx.x == 0 && tid == 0) *cnt = 0u;
    // ---- pack path ----
    const int g = tid >> 5, l = tid & 31;
    const int row = blockIdx.x * 8 + g;
    const int tok = (row < LCTX) ? ctok[row] : qtok[row - LCTX];
    const float4 v = *(const float4*)(emb + (size_t)tok * D + 4 * l);
    float p = v.x * v.x + v.y * v.y + v.z * v.z + v.w * v.w;
#pragma unroll
    for (int off = 16; off; off >>= 1) p += __shfl_xor(p, off, 32);
    if (l == 0 && row < LCTX) cn2[row] = p;
    const int c = l >> 1, h = l & 1;       // 16-B chunk, half-chunk
    const int pch = c ^ (row & 7);         // pre-swizzle
    uint2 pk = make_uint2(pack2(v.x, v.y), pack2(v.z, v.w));
    *(uint2*)(&cemb[(size_t)row * D + pch * 8 + h * 4]) = pk;
    return;
  }

  // ---- qprep path: 8 queries per block ----
  const int qb = (blockIdx.x - PACKB) * 8;
  {
    const int r = tid >> 5, l = tid & 31;
    const int tok = qtok[qb + r];
    *(float4*)(&sq[r][4 * l]) = *(const float4*)(emb + (size_t)tok * D + 4 * l);
  }
  const int d = tid & 127, qs = tid >> 7;  // thread handles queries qs,qs+2,qs+4,qs+6
  const float bv = bvec[d];
  float acc[4] = {bv, bv, bv, bv};
  for (int ch = 0; ch < 4; ++ch) {         // 32 k-rows of W per chunk
    __syncthreads();
#pragma unroll
    for (int j = 0; j < 4; ++j) {
      const int i4 = j * 256 + tid;        // 1024 float4 = 32x128 floats
      *(float4*)(&sW[i4 * 4]) = *(const float4*)(W + (size_t)ch * 32 * D + i4 * 4);
    }
    __syncthreads();
#pragma unroll
    for (int kk = 0; kk < 32; ++kk) {
      const float wv = sW[kk * D + d];
      const int k = ch * 32 + kk;
#pragma unroll
      for (int i = 0; i < 4; ++i) acc[i] = fmaf(sq[2 * i + qs][k], wv, acc[i]);
    }
  }
#pragma unroll
  for (int i = 0; i < 4; ++i) qp[(size_t)(qb + 2 * i + qs) * D + d] = acc[i];
}

// ---------------------------------------------------------------------------
// Kernel 2: coarse scores via bf16 MFMA + per-lane sorted top-4 (branchless
// v_med3_f32 ladder); 16 candidates per (query, chunk) written directly.
__global__ __launch_bounds__(512, 4) void dist_topk_kernel(
    const unsigned short* __restrict__ cemb, const float* __restrict__ cn2,
    float2* __restrict__ partials) {
  __shared__ __align__(16) unsigned short sCt[CSTEP * D];  // 32 KB
  __shared__ __align__(16) float scn2[CCHUNK];             // 2 KB

  const int tid = threadIdx.x;
  const int wid = tid >> 6, lane = tid & 63;
  const int n = lane & 15, qq = lane >> 4;   // query col, k-quad / C-row group
  const int chunk = blockIdx.x, qtile = blockIdx.y;
  const int qbase = qtile * QT, cbase0 = chunk * CCHUNK;

  scn2[tid] = cn2[cbase0 + tid];

  // ---- stage Q tile (128 rows) into sCt via DMA: 4 insts per wave ----
  {
    const unsigned short* qrowbase = cemb + (size_t)(LCTX + qbase) * D;
#pragma unroll
    for (int j = 0; j < 4; ++j) {
      const int r0 = wid * 16 + j * 4;  // 4 rows per inst (64 lanes x 16 B)
      const unsigned short* gp = qrowbase + r0 * D + lane * 8;
      __builtin_amdgcn_global_load_lds(
          (const __attribute__((address_space(1))) unsigned int*)gp,
          (__attribute__((address_space(3))) unsigned int*)&sCt[r0 * D], 16, 0, 0);
    }
  }
  __syncthreads();

  // ---- B-fragments from swizzled LDS: B[n][k=32kk+8qq+j] ----
  bf16x8 bq[4];
  {
    const int rq = wid * 16 + n;
#pragma unroll
    for (int kk = 0; kk < 4; ++kk)
      bq[kk] = *(const bf16x8*)(&sCt[rq * D + 8 * ((4 * kk + qq) ^ (rq & 7))]);
  }

  // ---- per-lane sorted top-4 (ascending; bs[3] is the acceptance bound) ----
  float bs[4] = {FINF, FINF, FINF, FINF};
  int bi[4] = {0, 0, 0, 0};

  for (int st = 0; st < CCHUNK / CSTEP; ++st) {
    const int cb = cbase0 + st * CSTEP;
    __syncthreads();  // previous step's LDS reads done in all waves
    // ---- stage 128 context rows: 4 DMA insts per wave (8 waves) ----
    {
      const unsigned short* crowbase = cemb + (size_t)cb * D;
#pragma unroll
      for (int j = 0; j < 4; ++j) {
        const int r0 = wid * 16 + j * 4;
        const unsigned short* gp = crowbase + r0 * D + lane * 8;
        __builtin_amdgcn_global_load_lds(
            (const __attribute__((address_space(1))) unsigned int*)gp,
            (__attribute__((address_space(3))) unsigned int*)&sCt[r0 * D], 16, 0, 0);
      }
    }
    __syncthreads();

    // ---- 8 tiles of 16 contexts: 4 MFMAs (K=128) + branchless selection ----
#pragma unroll
    for (int tt = 0; tt < 8; ++tt) {
      f32x4 acc = {0.f, 0.f, 0.f, 0.f};
      const int m = 16 * tt + n;  // LDS row; (global row)&7 == n&7
#pragma unroll
      for (int kk = 0; kk < 4; ++kk) {
        const bf16x8 af = *(const bf16x8*)(&sCt[m * D + 8 * ((4 * kk + qq) ^ (n & 7))]);
        acc = __builtin_amdgcn_mfma_f32_16x16x32_bf16(af, bq[kk], acc, 0, 0, 0);
      }
      // C/D: col=lane&15 (query), row = 4*qq + r (context within tile)
      const f32x4 cv = *(const f32x4*)(&scn2[st * CSTEP + 16 * tt + 4 * qq]);
      const int ibase = cb + 16 * tt + 4 * qq;
#pragma unroll
      for (int r = 0; r < 4; ++r) {
        const float v = fmaf(-2.f, acc[r], cv[r]);
        const int iv = ibase + r;
        const bool c0 = v < bs[0], c1 = v < bs[1], c2 = v < bs[2], c3 = v < bs[3];
        const float nb0 = fminf(bs[0], v);
        const float nb1 = __builtin_amdgcn_fmed3f(v, bs[0], bs[1]);
        const float nb2 = __builtin_amdgcn_fmed3f(v, bs[1], bs[2]);
        const float nb3 = __builtin_amdgcn_fmed3f(v, bs[2], bs[3]);
        const int ni0 = c0 ? iv : bi[0];
        const int ni1 = c1 ? (c0 ? bi[0] : iv) : bi[1];
        const int ni2 = c2 ? (c1 ? bi[1] : iv) : bi[2];
        const int ni3 = c3 ? (c2 ? bi[2] : iv) : bi[3];
        bs[0] = nb0; bs[1] = nb1; bs[2] = nb2; bs[3] = nb3;
        bi[0] = ni0; bi[1] = ni1; bi[2] = ni2; bi[3] = ni3;
      }
    }
  }

  // ---- direct write-out: 16 candidates per (query, chunk), no merge ----
  const int q = qbase + wid * 16 + n;
  float2* dst = partials + (size_t)q * NCANDTOT + chunk * PERCHUNK + qq * 4;
#pragma unroll
  for (int t = 0; t < 4; ++t)
    dst[t] = make_float2(bs[t], __int_as_float(bi[t]));
}

// ---------------------------------------------------------------------------
// Kernel 3 (fused merge + f64 refine + final + OUTPUT): one block per query.
// R12 post-mortem: per-kernel times are all < 43 us and shrinking them no
// longer moves dur_us — so this round removes a LAUNCH instead: the last
// select block (device-scope atomic counter, G16 pattern) computes the
// per-batch softmax and writes the final output, eliminating out_kernel.
__global__ __launch_bounds__(256) void select_kernel(
    const float2* __restrict__ partials, const int* __restrict__ qtok,
    const int* __restrict__ ctok, const float* __restrict__ emb,
    const float* __restrict__ qp, float* __restrict__ importance,
    unsigned* __restrict__ cnt, float* __restrict__ out) {
  __shared__ float2 swt[64];                 // 4 waves x 16 wave-top cands
  __shared__ double sd2[NCAND], sdp[NCAND];
  __shared__ int sid[NCAND];
  __shared__ double sred[4];
  const int tid = threadIdx.x;
  const int w = tid >> 6, lane = tid & 63;
  const int q = blockIdx.x;

  // ---- phase 1a: per-wave top-16 of 512 (float4 = 2 cands per load) ----
  float v[8]; int vi[8];
  const float4* pq4 = (const float4*)(partials + (size_t)q * NCANDTOT);
#pragma unroll
  for (int j = 0; j < 4; ++j) {
    const float4 cd = pq4[256 * j + tid];  // cands 512j+2tid, 512j+2tid+1
    v[2 * j] = cd.x;     vi[2 * j] = __float_as_int(cd.y);
    v[2 * j + 1] = cd.z; vi[2 * j + 1] = __float_as_int(cd.w);
  }
  unsigned consumed = 0;
#pragma unroll
  for (int t = 0; t < NCAND; ++t) {
    float lmin = FINF; int li = 0x7fffffff; int ls = 0;
#pragma unroll
    for (int j = 0; j < 8; ++j) {
      const bool take = !((consumed >> j) & 1u) && (v[j] < lmin);
      lmin = take ? v[j] : lmin;
      li = take ? vi[j] : li;
      ls = take ? j : ls;
    }
    float m = lmin; int pidx = li; int pwho = (lane << 3) | ls;
#pragma unroll
    for (int off = 32; off; off >>= 1) {
      const float om = __shfl_xor(m, off, 64);
      const int oi = __shfl_xor(pidx, off, 64);
      const int ow = __shfl_xor(pwho, off, 64);
      const bool better = (om < m) || (om == m && oi < pidx);
      m = better ? om : m; pidx = better ? oi : pidx; pwho = better ? ow : pwho;
    }
    if ((pwho >> 3) == lane) consumed |= 1u << (pwho & 7);
    if (lane == t) swt[w * 16 + t] = make_float2(m, __int_as_float(pidx));
  }
  __syncthreads();

  // ---- phase 1b: wave 0 takes top-16 of the 64 wave-survivors ----
  if (w == 0) {
    const float2 cd = swt[lane];
    const float mv = cd.x; const int mi = __float_as_int(cd.y);
    bool cons = false;
#pragma unroll
    for (int t = 0; t < NCAND; ++t) {
      float m = cons ? FINF : mv;
      int pidx = cons ? 0x7fffffff : mi;
      int pwho = lane;
#pragma unroll
      for (int off = 32; off; off >>= 1) {
        const float om = __shfl_xor(m, off, 64);
        const int oi = __shfl_xor(pidx, off, 64);
        const int ow = __shfl_xor(pwho, off, 64);
        const bool better = (om < m) || (om == m && oi < pidx);
        m = better ? om : m; pidx = better ? oi : pidx; pwho = better ? ow : pwho;
      }
      if (pwho == lane) cons = true;
      if (lane == t) sid[t] = pidx;
    }
  }
  __syncthreads();

  // ---- phase 2: f64 refine; cand c = tid>>4, 8 dims per lane ----
  const int c = tid >> 4, sub = tid & 15;
  const int idx = sid[c];
  const int tc = ctok[idx];
  const int tq = qtok[q];
  const float* crow = emb + (size_t)tc * D + sub * 8;
  const float* qrow = emb + (size_t)tq * D + sub * 8;
  const float* prow = qp + (size_t)q * D + sub * 8;
  double dd = 0.0, pp = 0.0;
#pragma unroll
  for (int kk = 0; kk < 2; ++kk) {
    const float4 cv = *(const float4*)(crow + 4 * kk);
    const float4 qv = *(const float4*)(qrow + 4 * kk);
    const float4 pv = *(const float4*)(prow + 4 * kk);
    const double dx = (double)qv.x - (double)cv.x, dy = (double)qv.y - (double)cv.y;
    const double dz = (double)qv.z - (double)cv.z, dw = (double)qv.w - (double)cv.w;
    dd += dx * dx + dy * dy + dz * dz + dw * dw;
    pp += (double)pv.x * (double)cv.x + (double)pv.y * (double)cv.y +
          (double)pv.z * (double)cv.z + (double)pv.w * (double)cv.w;
  }
#pragma unroll
  for (int off = 1; off <= 8; off <<= 1) {
    dd += __shfl_xor(dd, off, 64);
    pp += __shfl_xor(pp, off, 64);
  }
  if (sub == 0) { sd2[c] = dd; sdp[c] = pp; }
  __syncthreads();

  // ---- phase 3: thread 0 serial exact top-8 + logits + max-softmax ----
  if (tid == 0) {
    bool used[NCAND];
#pragma unroll
    for (int n2 = 0; n2 < NCAND; ++n2) used[n2] = false;
    double lg[TOPN];
    for (int t = 0; t < TOPN; ++t) {
      int best = -1;
      for (int n2 = 0; n2 < NCAND; ++n2) {
        if (used[n2]) continue;
        if (best < 0 || sd2[n2] < sd2[best] ||
            (sd2[n2] == sd2[best] && sid[n2] < sid[best])) best = n2;
      }
      used[best] = true;
      lg[t] = sdp[best] * 0.08838834764831843 - sqrt(sd2[best] + 1e-12);
    }
    double m = lg[0];
#pragma unroll
    for (int t = 1; t < TOPN; ++t) m = fmax(m, lg[t]);
    double sum = 0.0;
#pragma unroll
    for (int t = 0; t < TOPN; ++t) sum += exp(lg[t] - m);
    importance[q] = (float)(1.0 / sum);  // max softmax = 1/sum
  }

  // ---- finisher: last block computes per-batch softmax + writes output ----
  __syncthreads();
  __shared__ unsigned sdone;
  if (tid == 0) {
    __threadfence();                 // release importance[q] device-wide
    sdone = atomicAdd(cnt, 1u);
  }
  __syncthreads();
  if (sdone != NQ - 1) return;
  __threadfence();                   // acquire all importance[] writes

  // 4 waves, wave w handles batch w (128 queries, 2 per lane)
  const volatile float* vimp = importance;
  const double v0 = (double)vimp[w * 128 + lane];
  const double v1 = (double)vimp[w * 128 + 64 + lane];
  double mx = fmax(v0, v1);
#pragma unroll
  for (int off = 32; off; off >>= 1) mx = fmax(mx, __shfl_xor(mx, off, 64));
  const double e0 = exp(v0 - mx), e1 = exp(v1 - mx);
  double s = e0 + e1;
#pragma unroll
  for (int off = 32; off; off >>= 1) s += __shfl_xor(s, off, 64);
  out[w * 128 + lane] = (float)((double)qtok[w * 128 + lane] * (e0 / s) * 128.0);
  out[w * 128 + 64 + lane] = (float)((double)qtok[w * 128 + 64 + lane] * (e1 / s) * 128.0);
}

// ---------------------------------------------------------------------------
extern "C" void kernel_launch(void* const* d_in, const int* in_sizes, int n_in,
                              void* d_out, int out_size, void* d_ws, size_t ws_size,
                              hipStream_t stream) {
  const int* qtok = (const int*)d_in[0];
  const int* ctok = (const int*)d_in[1];
  const float* emb = (const float*)d_in[2];
  const float* W = (const float*)d_in[3];
  const float* bvec = (const float*)d_in[4];
  float* out = (float*)d_out;

  char* ws = (char*)d_ws;
  float* cn2 = (float*)ws;                               // 256 KB
  float* qp = cn2 + LCTX;                                // 256 KB
  float* imp = qp + (size_t)NQ * D;                      // 2 KB
  unsigned* cnt = (unsigned*)(imp + NQ);                 // 4 B (+pad to 16 B)
  unsigned short* cemb = (unsigned short*)(cnt + 4);     // 16.9 MB (16B-aligned)
  float2* partials = (float2*)(cemb + (size_t)NROWS * D);// 8.4 MB
  // total ws ~= 25.8 MB

  prep_kernel<<<PACKB + QPREPB, 256, 0, stream>>>(ctok, qtok, emb, W, bvec,
                                                  cemb, cn2, qp, cnt);
  dist_topk_kernel<<<dim3(NCH, NQT), 512, 0, stream>>>(cemb, cn2, partials);
  select_kernel<<<NQ, 256, 0, stream>>>(partials, qtok, ctok, emb, qp, imp,
                                        cnt, out);
}

// Round 14
// 142.531 us; speedup vs baseline: 1.1557x; 1.1557x over previous
//
#include <hip/hip_runtime.h>
#include <math.h>

// Problem constants
#define D      128
#define NQ     512          // B * LQ = 4 * 128
#define LCTX   65536
#define TOPN   8
#define NCAND  16           // coarse candidates refined in f64
// Distance-kernel tiling
#define QT     128          // queries per block (8 waves x 16)
#define CCHUNK 512          // contexts per block
#define CSTEP  128          // contexts staged per LDS step
#define NCH    (LCTX / CCHUNK)    // 128 chunks
#define PERCHUNK 16               // candidates stored per (query, chunk)
#define NCANDTOT (NCH * PERCHUNK) // 2048 coarse candidates per query
#define NQT    (NQ / QT)          // 4 query tiles
#define NROWS  (LCTX + NQ)        // packed table rows (contexts then queries)
#define PACKB  (NROWS / 8)        // 8256 pack blocks
#define QPREPB (NQ / 8)           // 64 qprep blocks
#define FINF   3.0e38f

typedef __attribute__((ext_vector_type(8))) __bf16 bf16x8;
typedef __attribute__((ext_vector_type(4))) float f32x4;

// pack two f32 -> two bf16 (round-to-nearest-ish; coarse path only)
static __device__ __forceinline__ unsigned pack2(float a, float b) {
  const unsigned ua = (__float_as_uint(a) + 0x8000u) >> 16;
  const unsigned ub = (__float_as_uint(b) + 0x8000u) & 0xffff0000u;
  return ua | ub;
}

// ---------------------------------------------------------------------------
// Kernel 1 (fused prep): blocks [0,PACKB) gather+pack all rows to bf16 cemb
// (chunk-XOR-pre-swizzled) + cn2; blocks [PACKB,PACKB+QPREPB) compute
// qp = q @ W + b with W staged in 16-KB chunks.
__global__ __launch_bounds__(256) void prep_kernel(const int* __restrict__ ctok,
                                                   const int* __restrict__ qtok,
                                                   const float* __restrict__ emb,
                                                   const float* __restrict__ W,
                                                   const float* __restrict__ bvec,
                                                   unsigned short* __restrict__ cemb,
                                                   float* __restrict__ cn2,
                                                   float* __restrict__ qp) {
  __shared__ float sW[32 * D];  // 16 KB (qprep path)
  __shared__ float sq[8][D];    // 4 KB
  const int tid = threadIdx.x;

  if (blockIdx.x < PACKB) {
    // ---- pack path ----
    const int g = tid >> 5, l = tid & 31;
    const int row = blockIdx.x * 8 + g;
    const int tok = (row < LCTX) ? ctok[row] : qtok[row - LCTX];
    const float4 v = *(const float4*)(emb + (size_t)tok * D + 4 * l);
    float p = v.x * v.x + v.y * v.y + v.z * v.z + v.w * v.w;
#pragma unroll
    for (int off = 16; off; off >>= 1) p += __shfl_xor(p, off, 32);
    if (l == 0 && row < LCTX) cn2[row] = p;
    const int c = l >> 1, h = l & 1;       // 16-B chunk, half-chunk
    const int pch = c ^ (row & 7);         // pre-swizzle
    uint2 pk = make_uint2(pack2(v.x, v.y), pack2(v.z, v.w));
    *(uint2*)(&cemb[(size_t)row * D + pch * 8 + h * 4]) = pk;
    return;
  }

  // ---- qprep path: 8 queries per block ----
  const int qb = (blockIdx.x - PACKB) * 8;
  {
    const int r = tid >> 5, l = tid & 31;
    const int tok = qtok[qb + r];
    *(float4*)(&sq[r][4 * l]) = *(const float4*)(emb + (size_t)tok * D + 4 * l);
  }
  const int d = tid & 127, qs = tid >> 7;  // thread handles queries qs,qs+2,qs+4,qs+6
  const float bv = bvec[d];
  float acc[4] = {bv, bv, bv, bv};
  for (int ch = 0; ch < 4; ++ch) {         // 32 k-rows of W per chunk
    __syncthreads();
#pragma unroll
    for (int j = 0; j < 4; ++j) {
      const int i4 = j * 256 + tid;        // 1024 float4 = 32x128 floats
      *(float4*)(&sW[i4 * 4]) = *(const float4*)(W + (size_t)ch * 32 * D + i4 * 4);
    }
    __syncthreads();
#pragma unroll
    for (int kk = 0; kk < 32; ++kk) {
      const float wv = sW[kk * D + d];
      const int k = ch * 32 + kk;
#pragma unroll
      for (int i = 0; i < 4; ++i) acc[i] = fmaf(sq[2 * i + qs][k], wv, acc[i]);
    }
  }
#pragma unroll
  for (int i = 0; i < 4; ++i) qp[(size_t)(qb + 2 * i + qs) * D + d] = acc[i];
}

// ---------------------------------------------------------------------------
// Kernel 2: coarse scores via bf16 MFMA + per-lane sorted top-4 (branchless
// v_med3_f32 ladder); 16 candidates per (query, chunk) written directly.
__global__ __launch_bounds__(512, 4) void dist_topk_kernel(
    const unsigned short* __restrict__ cemb, const float* __restrict__ cn2,
    float2* __restrict__ partials) {
  __shared__ __align__(16) unsigned short sCt[CSTEP * D];  // 32 KB
  __shared__ __align__(16) float scn2[CCHUNK];             // 2 KB

  const int tid = threadIdx.x;
  const int wid = tid >> 6, lane = tid & 63;
  const int n = lane & 15, qq = lane >> 4;   // query col, k-quad / C-row group
  const int chunk = blockIdx.x, qtile = blockIdx.y;
  const int qbase = qtile * QT, cbase0 = chunk * CCHUNK;

  scn2[tid] = cn2[cbase0 + tid];

  // ---- stage Q tile (128 rows) into sCt via DMA: 4 insts per wave ----
  {
    const unsigned short* qrowbase = cemb + (size_t)(LCTX + qbase) * D;
#pragma unroll
    for (int j = 0; j < 4; ++j) {
      const int r0 = wid * 16 + j * 4;  // 4 rows per inst (64 lanes x 16 B)
      const unsigned short* gp = qrowbase + r0 * D + lane * 8;
      __builtin_amdgcn_global_load_lds(
          (const __attribute__((address_space(1))) unsigned int*)gp,
          (__attribute__((address_space(3))) unsigned int*)&sCt[r0 * D], 16, 0, 0);
    }
  }
  __syncthreads();

  // ---- B-fragments from swizzled LDS: B[n][k=32kk+8qq+j] ----
  bf16x8 bq[4];
  {
    const int rq = wid * 16 + n;
#pragma unroll
    for (int kk = 0; kk < 4; ++kk)
      bq[kk] = *(const bf16x8*)(&sCt[rq * D + 8 * ((4 * kk + qq) ^ (rq & 7))]);
  }

  // ---- per-lane sorted top-4 (ascending; bs[3] is the acceptance bound) ----
  float bs[4] = {FINF, FINF, FINF, FINF};
  int bi[4] = {0, 0, 0, 0};

  for (int st = 0; st < CCHUNK / CSTEP; ++st) {
    const int cb = cbase0 + st * CSTEP;
    __syncthreads();  // previous step's LDS reads done in all waves
    // ---- stage 128 context rows: 4 DMA insts per wave (8 waves) ----
    {
      const unsigned short* crowbase = cemb + (size_t)cb * D;
#pragma unroll
      for (int j = 0; j < 4; ++j) {
        const int r0 = wid * 16 + j * 4;
        const unsigned short* gp = crowbase + r0 * D + lane * 8;
        __builtin_amdgcn_global_load_lds(
            (const __attribute__((address_space(1))) unsigned int*)gp,
            (__attribute__((address_space(3))) unsigned int*)&sCt[r0 * D], 16, 0, 0);
      }
    }
    __syncthreads();

    // ---- 8 tiles of 16 contexts: 4 MFMAs (K=128) + branchless selection ----
#pragma unroll
    for (int tt = 0; tt < 8; ++tt) {
      f32x4 acc = {0.f, 0.f, 0.f, 0.f};
      const int m = 16 * tt + n;  // LDS row; (global row)&7 == n&7
#pragma unroll
      for (int kk = 0; kk < 4; ++kk) {
        const bf16x8 af = *(const bf16x8*)(&sCt[m * D + 8 * ((4 * kk + qq) ^ (n & 7))]);
        acc = __builtin_amdgcn_mfma_f32_16x16x32_bf16(af, bq[kk], acc, 0, 0, 0);
      }
      // C/D: col=lane&15 (query), row = 4*qq + r (context within tile)
      const f32x4 cv = *(const f32x4*)(&scn2[st * CSTEP + 16 * tt + 4 * qq]);
      const int ibase = cb + 16 * tt + 4 * qq;
#pragma unroll
      for (int r = 0; r < 4; ++r) {
        const float v = fmaf(-2.f, acc[r], cv[r]);
        const int iv = ibase + r;
        const bool c0 = v < bs[0], c1 = v < bs[1], c2 = v < bs[2], c3 = v < bs[3];
        const float nb0 = fminf(bs[0], v);
        const float nb1 = __builtin_amdgcn_fmed3f(v, bs[0], bs[1]);
        const float nb2 = __builtin_amdgcn_fmed3f(v, bs[1], bs[2]);
        const float nb3 = __builtin_amdgcn_fmed3f(v, bs[2], bs[3]);
        const int ni0 = c0 ? iv : bi[0];
        const int ni1 = c1 ? (c0 ? bi[0] : iv) : bi[1];
        const int ni2 = c2 ? (c1 ? bi[1] : iv) : bi[2];
        const int ni3 = c3 ? (c2 ? bi[2] : iv) : bi[3];
        bs[0] = nb0; bs[1] = nb1; bs[2] = nb2; bs[3] = nb3;
        bi[0] = ni0; bi[1] = ni1; bi[2] = ni2; bi[3] = ni3;
      }
    }
  }

  // ---- direct write-out: 16 candidates per (query, chunk), no merge ----
  const int q = qbase + wid * 16 + n;
  float2* dst = partials + (size_t)q * NCANDTOT + chunk * PERCHUNK + qq * 4;
#pragma unroll
  for (int t = 0; t < 4; ++t)
    dst[t] = make_float2(bs[t], __int_as_float(bi[t]));
}

// ---------------------------------------------------------------------------
// Kernel 3 (fused merge + f64 refine + final): one block per query.
// R13 post-mortem: phase 3 was a SERIAL thread-0 selection sort over LDS f64
// (~128 iters x ~2 dependent 120-cyc LDS reads ~= 13 us with 255 lanes idle),
// and the atomic+fence finisher cost another ~8 us.  Finisher reverted; phase
// 3 is now an exact all-pairs rank (15 intra-16-group shfl_xor, idx
// tie-break) computed in parallel by wave-0 lanes 0-15.
__global__ __launch_bounds__(256) void select_kernel(
    const float2* __restrict__ partials, const int* __restrict__ qtok,
    const int* __restrict__ ctok, const float* __restrict__ emb,
    const float* __restrict__ qp, float* __restrict__ importance) {
  __shared__ float2 swt[64];                 // 4 waves x 16 wave-top cands
  __shared__ double sd2[NCAND], sdp[NCAND];
  __shared__ int sid[NCAND];
  const int tid = threadIdx.x;
  const int w = tid >> 6, lane = tid & 63;
  const int q = blockIdx.x;

  // ---- phase 1a: per-wave top-16 of 512 (float4 = 2 cands per load) ----
  float v[8]; int vi[8];
  const float4* pq4 = (const float4*)(partials + (size_t)q * NCANDTOT);
#pragma unroll
  for (int j = 0; j < 4; ++j) {
    const float4 cd = pq4[256 * j + tid];  // cands 512j+2tid, 512j+2tid+1
    v[2 * j] = cd.x;     vi[2 * j] = __float_as_int(cd.y);
    v[2 * j + 1] = cd.z; vi[2 * j + 1] = __float_as_int(cd.w);
  }
  unsigned consumed = 0;
#pragma unroll
  for (int t = 0; t < NCAND; ++t) {
    float lmin = FINF; int li = 0x7fffffff; int ls = 0;
#pragma unroll
    for (int j = 0; j < 8; ++j) {
      const bool take = !((consumed >> j) & 1u) && (v[j] < lmin);
      lmin = take ? v[j] : lmin;
      li = take ? vi[j] : li;
      ls = take ? j : ls;
    }
    float m = lmin; int pidx = li; int pwho = (lane << 3) | ls;
#pragma unroll
    for (int off = 32; off; off >>= 1) {
      const float om = __shfl_xor(m, off, 64);
      const int oi = __shfl_xor(pidx, off, 64);
      const int ow = __shfl_xor(pwho, off, 64);
      const bool better = (om < m) || (om == m && oi < pidx);
      m = better ? om : m; pidx = better ? oi : pidx; pwho = better ? ow : pwho;
    }
    if ((pwho >> 3) == lane) consumed |= 1u << (pwho & 7);
    if (lane == t) swt[w * 16 + t] = make_float2(m, __int_as_float(pidx));
  }
  __syncthreads();

  // ---- phase 1b: wave 0 takes top-16 of the 64 wave-survivors ----
  if (w == 0) {
    const float2 cd = swt[lane];
    const float mv = cd.x; const int mi = __float_as_int(cd.y);
    bool cons = false;
#pragma unroll
    for (int t = 0; t < NCAND; ++t) {
      float m = cons ? FINF : mv;
      int pidx = cons ? 0x7fffffff : mi;
      int pwho = lane;
#pragma unroll
      for (int off = 32; off; off >>= 1) {
        const float om = __shfl_xor(m, off, 64);
        const int oi = __shfl_xor(pidx, off, 64);
        const int ow = __shfl_xor(pwho, off, 64);
        const bool better = (om < m) || (om == m && oi < pidx);
        m = better ? om : m; pidx = better ? oi : pidx; pwho = better ? ow : pwho;
      }
      if (pwho == lane) cons = true;
      if (lane == t) sid[t] = pidx;
    }
  }
  __syncthreads();

  // ---- phase 2: f64 refine; cand c = tid>>4, 8 dims per lane ----
  const int c = tid >> 4, sub = tid & 15;
  const int idx = sid[c];
  const int tc = ctok[idx];
  const int tq = qtok[q];
  const float* crow = emb + (size_t)tc * D + sub * 8;
  const float* qrow = emb + (size_t)tq * D + sub * 8;
  const float* prow = qp + (size_t)q * D + sub * 8;
  double dd = 0.0, pp = 0.0;
#pragma unroll
  for (int kk = 0; kk < 2; ++kk) {
    const float4 cv = *(const float4*)(crow + 4 * kk);
    const float4 qv = *(const float4*)(qrow + 4 * kk);
    const float4 pv = *(const float4*)(prow + 4 * kk);
    const double dx = (double)qv.x - (double)cv.x, dy = (double)qv.y - (double)cv.y;
    const double dz = (double)qv.z - (double)cv.z, dw = (double)qv.w - (double)cv.w;
    dd += dx * dx + dy * dy + dz * dz + dw * dw;
    pp += (double)pv.x * (double)cv.x + (double)pv.y * (double)cv.y +
          (double)pv.z * (double)cv.z + (double)pv.w * (double)cv.w;
  }
#pragma unroll
  for (int off = 1; off <= 8; off <<= 1) {
    dd += __shfl_xor(dd, off, 64);
    pp += __shfl_xor(pp, off, 64);
  }
  if (sub == 0) { sd2[c] = dd; sdp[c] = pp; }
  __syncthreads();

  // ---- phase 3 (parallel): wave-0 lanes 0..15, one candidate each ----
  if (w == 0 && lane < NCAND) {
    const double d2 = sd2[lane];
    const double dp = sdp[lane];
    const int cid = sid[lane];
    // exact rank via all-pairs compares within the 16-lane group
    int rank = 0;
#pragma unroll
    for (int off = 1; off < NCAND; ++off) {
      const double od = __shfl_xor(d2, off, 64);
      const int oc = __shfl_xor(cid, off, 64);
      rank += (od < d2 || (od == d2 && oc < cid)) ? 1 : 0;
    }
    const bool sel = (rank < TOPN);
    const double lg = sel
        ? dp * 0.08838834764831843 - sqrt(d2 + 1e-12)
        : -1.0e300;
    // softmax over the 8 selected (group max via shfl offs 1,2,4,8)
    double mx = lg;
#pragma unroll
    for (int off = 1; off <= 8; off <<= 1) mx = fmax(mx, __shfl_xor(mx, off, 64));
    const double e = sel ? exp(lg - mx) : 0.0;
    double s = e;
#pragma unroll
    for (int off = 1; off <= 8; off <<= 1) s += __shfl_xor(s, off, 64);
    if (lane == 0) importance[q] = (float)(1.0 / s);  // max softmax = 1/sum
  }
}

// ---------------------------------------------------------------------------
// Kernel 4: softmax over Lq per batch, write reconstructed query (f64 internal).
__global__ __launch_bounds__(128) void out_kernel(const float* __restrict__ importance,
                                                  const int* __restrict__ qtok,
                                                  float* __restrict__ out) {
  const int b = blockIdx.x, i = threadIdx.x;  // 4 blocks x 128 threads
  __shared__ double sred[2];
  const double v = (double)importance[b * 128 + i];
  double m = v;
#pragma unroll
  for (int off = 32; off; off >>= 1) m = fmax(m, __shfl_xor(m, off, 64));
  if ((i & 63) == 0) sred[i >> 6] = m;
  __syncthreads();
  const double M = fmax(sred[0], sred[1]);
  const double e = exp(v - M);
  double s = e;
#pragma unroll
  for (int off = 32; off; off >>= 1) s += __shfl_xor(s, off, 64);
  __syncthreads();
  if ((i & 63) == 0) sred[i >> 6] = s;
  __syncthreads();
  const double S = sred[0] + sred[1];
  out[b * 128 + i] = (float)((double)qtok[b * 128 + i] * (e / S) * 128.0);
}

// ---------------------------------------------------------------------------
extern "C" void kernel_launch(void* const* d_in, const int* in_sizes, int n_in,
                              void* d_out, int out_size, void* d_ws, size_t ws_size,
                              hipStream_t stream) {
  const int* qtok = (const int*)d_in[0];
  const int* ctok = (const int*)d_in[1];
  const float* emb = (const float*)d_in[2];
  const float* W = (const float*)d_in[3];
  const float* bvec = (const float*)d_in[4];
  float* out = (float*)d_out;

  char* ws = (char*)d_ws;
  float* cn2 = (float*)ws;                               // 256 KB
  float* qp = cn2 + LCTX;                                // 256 KB
  float* imp = qp + (size_t)NQ * D;                      // 2 KB
  unsigned short* cemb = (unsigned short*)(imp + NQ);    // 16.9 MB (16B-aligned)
  float2* partials = (float2*)(cemb + (size_t)NROWS * D);// 8.4 MB
  // total ws ~= 25.8 MB

  prep_kernel<<<PACKB + QPREPB, 256, 0, stream>>>(ctok, qtok, emb, W, bvec,
                                                  cemb, cn2, qp);
  dist_topk_kernel<<<dim3(NCH, NQT), 512, 0, stream>>>(cemb, cn2, partials);
  select_kernel<<<NQ, 256, 0, stream>>>(partials, qtok, ctok, emb, qp, imp);
  out_kernel<<<4, 128, 0, stream>>>(imp, qtok, out);
}